// Round 2
// baseline (436.354 us; speedup 1.0000x reference)
//
#include <hip/hip_runtime.h>
#include <hip/hip_bf16.h>
#include <math.h>

// Problem constants (fixed by reference)
#define B_TREES 64
#define N_NODES 65536
#define D 1024          // D_MEM == D_HID == 1024
#define D4 (D/4)        // 256 float4 per row

// ---------------- Kernel 1: prefix offsets from lens (int32 or int64) -------
// JAX default config downcasts jnp.int64 -> int32; autodetect: if the 64
// values read as int32 sum to N, it's int32; else read as int64 pairs.
__global__ void offsets_kernel(const int* __restrict__ lens32, int* __restrict__ off) {
    if (threadIdx.x == 0 && blockIdx.x == 0) {
        long long s32 = 0;
        for (int b = 0; b < B_TREES; ++b) s32 += lens32[b];
        const bool is32 = (s32 == (long long)N_NODES);
        int acc = 0;
        off[0] = 0;
        for (int b = 0; b < B_TREES; ++b) {
            int len = is32 ? lens32[b] : (int)(((const long long*)lens32)[b]);
            acc += len;
            off[b + 1] = acc;
        }
    }
}

// ---------------- Kernel 2: v = ds @ W   (v[b][m] = sum_h ds[b][h]*W[h][m]) ----
// grid: (4 m-tiles of 256, 16 b-groups of 4, 8 h-chunks of 128); block 256
__global__ void v_kernel(const float* __restrict__ ds, const float* __restrict__ W,
                         float* __restrict__ v) {
    const int m  = blockIdx.x * 256 + threadIdx.x;
    const int b0 = blockIdx.y * 4;
    const int h0 = blockIdx.z * 128;
    float acc[4] = {0.f, 0.f, 0.f, 0.f};
    for (int h = h0; h < h0 + 128; ++h) {
        float wv = W[h * D + m];                // coalesced across threads
        #pragma unroll
        for (int j = 0; j < 4; ++j)
            acc[j] += ds[(b0 + j) * D + h] * wv; // wave-uniform -> scalar loads
    }
    #pragma unroll
    for (int j = 0; j < 4; ++j)
        atomicAdd(&v[(b0 + j) * D + m], acc[j]);
}

// ---------------- Kernel 3: scores[n] = mb[n] . v[seg[n]] ----------------
// one wave (64 lanes) per node; block = 4 waves; grid = N/4
__global__ void scores_kernel(const float4* __restrict__ mb, const float4* __restrict__ v,
                              const int* __restrict__ off, float* __restrict__ scores,
                              int* __restrict__ segarr) {
    const int wave = threadIdx.x >> 6;
    const int lane = threadIdx.x & 63;
    const int node = blockIdx.x * 4 + wave;

    // binary search: largest b with off[b] <= node
    int lo = 0, hi = B_TREES - 1;
    while (lo < hi) {
        int mid = (lo + hi + 1) >> 1;
        if (off[mid] <= node) lo = mid; else hi = mid - 1;
    }

    const float4* mrow = mb + (size_t)node * D4;
    const float4* vrow = v  + (size_t)lo   * D4;
    float acc = 0.f;
    #pragma unroll
    for (int k = 0; k < 4; ++k) {
        float4 a = mrow[k * 64 + lane];
        float4 c = vrow[k * 64 + lane];
        acc += a.x * c.x + a.y * c.y + a.z * c.z + a.w * c.w;
    }
    #pragma unroll
    for (int o = 32; o > 0; o >>= 1) acc += __shfl_down(acc, o, 64);
    if (lane == 0) {
        scores[node] = acc;
        segarr[node] = lo;
    }
}

// ---------------- Kernel 4: per-segment softmax stats + normalize in place ----
// grid = 64 blocks (one per tree); scores[] -> attn weights w[]
__global__ void softmax_kernel(const int* __restrict__ off, float* __restrict__ scores) {
    const int b  = blockIdx.x;
    const int s0 = off[b], s1 = off[b + 1];
    const int tid = threadIdx.x;
    __shared__ float red[256];

    float mloc = -INFINITY;
    for (int i = s0 + tid; i < s1; i += 256) mloc = fmaxf(mloc, scores[i]);
    red[tid] = mloc; __syncthreads();
    for (int s = 128; s > 0; s >>= 1) {
        if (tid < s) red[tid] = fmaxf(red[tid], red[tid + s]);
        __syncthreads();
    }
    const float m = red[0]; __syncthreads();

    float zloc = 0.f;
    for (int i = s0 + tid; i < s1; i += 256) zloc += __expf(scores[i] - m);
    red[tid] = zloc; __syncthreads();
    for (int s = 128; s > 0; s >>= 1) {
        if (tid < s) red[tid] += red[tid + s];
        __syncthreads();
    }
    const float inv = 1.f / red[0]; __syncthreads();

    for (int i = s0 + tid; i < s1; i += 256)
        scores[i] = __expf(scores[i] - m) * inv;
}

// ---------------- Kernel 5: context[seg] += w[n] * mb[n] ----------------
// block owns CHUNK=64 contiguous nodes; thread t owns float4 at d = 4t.
// Flush to global with atomicAdd only at segment boundaries.
__global__ void ctx_kernel(const float4* __restrict__ mb, const float* __restrict__ w,
                           const int* __restrict__ segarr, float* __restrict__ out) {
    const int n0 = blockIdx.x * 64;
    const int t  = threadIdx.x; // 0..255
    float4 acc = make_float4(0.f, 0.f, 0.f, 0.f);
    int cur = segarr[n0];
    for (int i = 0; i < 64; ++i) {
        const int n = n0 + i;
        const int s = segarr[n];          // wave-uniform
        if (s != cur) {                   // wave-uniform branch
            float* o = out + (size_t)cur * D + t * 4;
            atomicAdd(o + 0, acc.x); atomicAdd(o + 1, acc.y);
            atomicAdd(o + 2, acc.z); atomicAdd(o + 3, acc.w);
            acc = make_float4(0.f, 0.f, 0.f, 0.f);
            cur = s;
        }
        const float wv = w[n];            // wave-uniform scalar load
        const float4 m4 = mb[(size_t)n * D4 + t];
        acc.x += wv * m4.x; acc.y += wv * m4.y;
        acc.z += wv * m4.z; acc.w += wv * m4.w;
    }
    float* o = out + (size_t)cur * D + t * 4;
    atomicAdd(o + 0, acc.x); atomicAdd(o + 1, acc.y);
    atomicAdd(o + 2, acc.z); atomicAdd(o + 3, acc.w);
}

extern "C" void kernel_launch(void* const* d_in, const int* in_sizes, int n_in,
                              void* d_out, int out_size, void* d_ws, size_t ws_size,
                              hipStream_t stream) {
    const float* mb   = (const float*)d_in[0];       // [N, 1024]
    const float* ds   = (const float*)d_in[1];       // [64, 1024]
    const float* W    = (const float*)d_in[2];       // [1024, 1024]
    const int*   lens = (const int*)d_in[3];         // [64] int32 (or int64 — autodetected)
    float*       out  = (float*)d_out;               // [64, 1024]

    // workspace layout
    char* ws = (char*)d_ws;
    int*   off    = (int*)ws;                                   // 80 ints (uses 65)
    float* v      = (float*)(ws + 512);                         // 64*1024 floats
    float* scores = (float*)(ws + 512 + 64 * D * 4);            // N floats (becomes w)
    int*   segarr = (int*)  (ws + 512 + 64 * D * 4 + N_NODES * 4); // N ints

    // zero atomic-accumulation targets
    hipMemsetAsync(v, 0, 64 * D * sizeof(float), stream);
    hipMemsetAsync(out, 0, B_TREES * D * sizeof(float), stream);

    offsets_kernel<<<1, 64, 0, stream>>>(lens, off);

    {
        dim3 grid(4, 16, 8);
        v_kernel<<<grid, 256, 0, stream>>>(ds, W, v);
    }

    scores_kernel<<<N_NODES / 4, 256, 0, stream>>>(
        (const float4*)mb, (const float4*)v, off, scores, segarr);

    softmax_kernel<<<B_TREES, 256, 0, stream>>>(off, scores);

    ctx_kernel<<<N_NODES / 64, 256, 0, stream>>>(
        (const float4*)mb, scores, segarr, out);
}